// Round 9
// baseline (765.625 us; speedup 1.0000x reference)
//
#include <hip/hip_runtime.h>
#include <hip/hip_bf16.h>

// Problem constants
#define B_   2
#define S_   2048
#define D_   4096
#define H_   32
#define HKV_ 8
#define HD_  128

typedef __bf16 bf16;
typedef __bf16 bf16x8 __attribute__((ext_vector_type(8)));
typedef __bf16 bf16x4 __attribute__((ext_vector_type(4)));
typedef float  f32x4  __attribute__((ext_vector_type(4)));

// ---------------- prep kernels ----------------

__global__ void cast_f32_bf16_kernel(const float* __restrict__ in, bf16* __restrict__ out, int n) {
    int i = (blockIdx.x * blockDim.x + threadIdx.x) * 4;
    if (i >= n) return;
    const float4 v = *(const float4*)(in + i);
    bf16x4 o;
    o[0] = (bf16)v.x; o[1] = (bf16)v.y; o[2] = (bf16)v.z; o[3] = (bf16)v.w;
    *(bf16x4*)(out + i) = o;
}

// W: K x N fp32 row-major  ->  WT: N x K bf16 row-major
__global__ void transpose_cast_kernel(const float* __restrict__ W, bf16* __restrict__ WT, int K, int N) {
    __shared__ float t[32][33];
    const int n0 = blockIdx.x * 32, k0 = blockIdx.y * 32;
    const int tx = threadIdx.x, ty = threadIdx.y;
    #pragma unroll
    for (int i = ty; i < 32; i += 8) t[i][tx] = W[(size_t)(k0 + i) * N + n0 + tx];
    __syncthreads();
    #pragma unroll
    for (int i = ty; i < 32; i += 8) WT[(size_t)(n0 + i) * K + k0 + tx] = (bf16)t[tx][i];
}

// V: (b,s) x (hk,d) bf16  ->  Vt: (b,hk,d) x s bf16
__global__ void transpose_v_kernel(const bf16* __restrict__ V, bf16* __restrict__ Vt) {
    __shared__ bf16 t[32][33];
    const int bh = blockIdx.z;            // b*HKV + hk
    const int b = bh >> 3, hk = bh & 7;
    const int d0 = blockIdx.x * 32, s0 = blockIdx.y * 32;
    const int tx = threadIdx.x, ty = threadIdx.y;
    #pragma unroll
    for (int i = ty; i < 32; i += 8)
        t[i][tx] = V[((size_t)(b * S_ + s0 + i)) * (HKV_ * HD_) + hk * HD_ + d0 + tx];
    __syncthreads();
    #pragma unroll
    for (int i = ty; i < 32; i += 8)
        Vt[((size_t)(bh * HD_ + d0 + i)) * S_ + s0 + tx] = t[tx][i];
}

// rotate-half RoPE in place on (B*S) x (nh*128) bf16, pos = row % S
__global__ void rope_kernel(bf16* __restrict__ T, int nh) {
    const int row = blockIdx.x;
    const int pos = row & (S_ - 1);
    const size_t base = (size_t)row * nh * HD_;
    const int npairs = nh * 64;
    const float c = 13.287712379549449f / 64.0f;   // log2(10000)/64
    for (int p = threadIdx.x; p < npairs; p += blockDim.x) {
        const int h = p >> 6, d = p & 63;
        const float invf = exp2f(-(float)d * c);
        const float ang = (float)pos * invf;
        float sn, cs;
        sincosf(ang, &sn, &cs);
        const size_t i1 = base + (size_t)h * HD_ + d;
        const size_t i2 = i1 + 64;
        const float a  = (float)T[i1];
        const float b2 = (float)T[i2];
        T[i1] = (bf16)(a * cs - b2 * sn);
        T[i2] = (bf16)(b2 * cs + a * sn);
    }
}

__device__ __forceinline__ void gload_lds16(const bf16* g, bf16* l) {
    __builtin_amdgcn_global_load_lds((const __attribute__((address_space(1))) void*)g,
                                     (__attribute__((address_space(3))) void*)l, 16, 0, 0);
}

// ---------------- GEMM 128x128 (m97 structure) — used for K/V projections ----------------

template <typename CT>
__global__ __launch_bounds__(256) void gemm_bt_kernel(const bf16* __restrict__ A,
                                                      const bf16* __restrict__ Bm,
                                                      CT* __restrict__ C,
                                                      int M, int N, int K) {
    __shared__ bf16 As[128 * 32];
    __shared__ bf16 Bs[128 * 32];
    const int m0 = blockIdx.x * 128, n0 = blockIdx.y * 128;
    const int tid = threadIdx.x;
    const int lane = tid & 63, wid = tid >> 6;
    const int wm = wid >> 1, wn = wid & 1;       // 2x2 waves -> 64x64 each
    const int lg = lane >> 4, lr = lane & 15;
    f32x4 acc[4][4] = {};
    const int arow = tid >> 2;
    const int achunk = (tid & 3) * 8;
    for (int k0 = 0; k0 < K; k0 += 32) {
        gload_lds16(A  + (size_t)(m0 + arow) * K      + k0 + achunk, As + tid * 8);
        gload_lds16(A  + (size_t)(m0 + 64 + arow) * K + k0 + achunk, As + 2048 + tid * 8);
        gload_lds16(Bm + (size_t)(n0 + arow) * K      + k0 + achunk, Bs + tid * 8);
        gload_lds16(Bm + (size_t)(n0 + 64 + arow) * K + k0 + achunk, Bs + 2048 + tid * 8);
        __syncthreads();
        bf16x8 af[4], bfv[4];
        #pragma unroll
        for (int i = 0; i < 4; i++) {
            af[i]  = *(const bf16x8*)(As + (wm * 64 + i * 16 + lr) * 32 + lg * 8);
            bfv[i] = *(const bf16x8*)(Bs + (wn * 64 + i * 16 + lr) * 32 + lg * 8);
        }
        #pragma unroll
        for (int mi = 0; mi < 4; mi++)
            #pragma unroll
            for (int ni = 0; ni < 4; ni++)
                acc[mi][ni] = __builtin_amdgcn_mfma_f32_16x16x32_bf16(af[mi], bfv[ni], acc[mi][ni], 0, 0, 0);
        __syncthreads();
    }
    #pragma unroll
    for (int mi = 0; mi < 4; mi++)
        #pragma unroll
        for (int ni = 0; ni < 4; ni++)
            #pragma unroll
            for (int r = 0; r < 4; r++) {
                const int row = m0 + wm * 64 + mi * 16 + lg * 4 + r;
                const int col = n0 + wn * 64 + ni * 16 + lr;
                C[(size_t)row * N + col] = (CT)acc[mi][ni][r];
            }
}

// ---------------- GEMM 256x256, BK=64, 8 waves, 8-phase pipelined (m201 structure) ----------------

#define PHASE256(QM, QN, STAGE_STMT, DO_VM)                                              \
    {                                                                                    \
        bf16x8 af[4][2], bfr[2][2];                                                      \
        _Pragma("unroll") for (int i = 0; i < 4; ++i) {                                  \
            const int row = wm * 128 + (QM * 4 + i) * 16 + lr;                           \
            _Pragma("unroll") for (int kk = 0; kk < 2; ++kk)                             \
                af[i][kk] = *(const bf16x8*)(curA + row * 64 + (((kk * 4 + lg) ^ (lr & 7)) << 3)); \
        }                                                                                \
        _Pragma("unroll") for (int i2 = 0; i2 < 2; ++i2) {                               \
            const int row = wn * 64 + (QN * 2 + i2) * 16 + lr;                           \
            _Pragma("unroll") for (int kk = 0; kk < 2; ++kk)                             \
                bfr[i2][kk] = *(const bf16x8*)(curB + row * 64 + (((kk * 4 + lg) ^ (lr & 7)) << 3)); \
        }                                                                                \
        STAGE_STMT;                                                                      \
        if (DO_VM) asm volatile("s_waitcnt vmcnt(4)" ::: "memory");                      \
        __builtin_amdgcn_s_barrier();                                                    \
        asm volatile("s_waitcnt lgkmcnt(0)" ::: "memory");                               \
        __builtin_amdgcn_sched_barrier(0);                                               \
        __builtin_amdgcn_s_setprio(1);                                                   \
        _Pragma("unroll") for (int i = 0; i < 4; ++i)                                    \
            _Pragma("unroll") for (int i2 = 0; i2 < 2; ++i2)                             \
                _Pragma("unroll") for (int kk = 0; kk < 2; ++kk)                         \
                    acc[QM * 4 + i][QN * 2 + i2] = __builtin_amdgcn_mfma_f32_16x16x32_bf16( \
                        af[i][kk], bfr[i2][kk], acc[QM * 4 + i][QN * 2 + i2], 0, 0, 0);  \
        __builtin_amdgcn_s_setprio(0);                                                   \
        __builtin_amdgcn_s_barrier();                                                    \
    }

template <typename CT>
__global__ __launch_bounds__(512, 2) void gemm_bt256_kernel(const bf16* __restrict__ A,
                                                            const bf16* __restrict__ Bm,
                                                            CT* __restrict__ C,
                                                            int M, int N, int K) {
    __shared__ bf16 sm[65536];   // 128 KiB
    const int nbx = N >> 8;
    const int cpx = gridDim.x >> 3;
    const int bid = blockIdx.x;
    const int swz = (bid & 7) * cpx + (bid >> 3);       // XCD swizzle (grid % 8 == 0)
    const int m0 = (swz / nbx) << 8;
    const int n0 = (swz % nbx) << 8;

    const int tid = threadIdx.x;
    const int w = tid >> 6, lane = tid & 63;
    const int wm = w >> 2, wn = w & 3;                  // 2 x 4 wave grid, 128x64 per wave
    const int lg = lane >> 4, lr = lane & 15;
    const int nkt = K >> 6;

    const bf16* Ab = A + (size_t)m0 * K;
    const bf16* Bb = Bm + (size_t)n0 * K;

    const int u8 = tid >> 3;
    const int schunk = ((tid & 7) ^ (u8 & 7)) << 3;     // pre-swizzled source col offset

    auto stageA = [&](int buf, int kt, int h) {
        bf16* dst = sm + buf * 32768 + h * 4096 + tid * 8;
        const bf16* src = Ab + (size_t)(h * 64 + u8) * K + kt * 64 + schunk;
        gload_lds16(src, dst);
        gload_lds16(src + (size_t)128 * K, dst + 8192);
    };
    auto stageB = [&](int buf, int kt, int h) {
        bf16* dst = sm + buf * 32768 + 16384 + h * 2048 + ((u8 >> 5) << 12) + ((u8 & 31) << 6) + ((tid & 7) << 3);
        const bf16* src = Bb + (size_t)(h * 32 + ((u8 >> 5) << 6) + (u8 & 31)) * K + kt * 64 + schunk;
        gload_lds16(src, dst);
        gload_lds16(src + (size_t)128 * K, dst + 8192);
    };

    f32x4 acc[8][4] = {};

    // prologue: tile0 fully -> buf0 (8 loads); tile1 B0,A0 -> buf1 (4 loads)
    stageA(0, 0, 0); stageA(0, 0, 1); stageB(0, 0, 0); stageB(0, 0, 1);
    stageB(1, 1, 0); stageA(1, 1, 0);
    asm volatile("s_waitcnt vmcnt(4)" ::: "memory");    // tile0 landed; tile1's 4 in flight
    __builtin_amdgcn_s_barrier();

    for (int t = 0; t < nkt; ++t) {
        const int cur = t & 1;
        const bf16* curA = sm + cur * 32768;
        const bf16* curB = curA + 16384;
        PHASE256(0, 0, { if (t + 1 < nkt) stageA(cur ^ 1, t + 1, 1); }, 0)
        PHASE256(1, 0, { if (t + 1 < nkt) stageB(cur ^ 1, t + 1, 1); }, 0)
        PHASE256(0, 1, { if (t + 2 < nkt) stageB(cur, t + 2, 0); }, 0)
        PHASE256(1, 1, { if (t + 2 < nkt) stageA(cur, t + 2, 0); }, 1)
    }

    #pragma unroll
    for (int mi = 0; mi < 8; ++mi)
        #pragma unroll
        for (int ni = 0; ni < 4; ++ni)
            #pragma unroll
            for (int r = 0; r < 4; ++r) {
                const int row = m0 + wm * 128 + mi * 16 + lg * 4 + r;
                const int col = n0 + wn * 64 + ni * 16 + lr;
                C[(size_t)row * N + col] = (CT)acc[mi][ni][r];
            }
}

// ---------------- flash attention (causal, GQA) ----------------
// Block = 256 threads = 4 waves = 4 q-heads of one GQA group, same 32 q-rows.
// DOUBLE-BUFFERED K/V tiles: stage(t+1) is issued BEFORE compute(t); the
// vmcnt(0) drain moves to after compute (loads have ~2500 cyc to land -> free).
// End-of-iter barrier = both "all waves done reading buf cur" and "t+1 landed".
#define KVB_ 64

__global__ __launch_bounds__(256) void attn_kernel(const bf16* __restrict__ Q,
                                                   const bf16* __restrict__ Kb,
                                                   const bf16* __restrict__ Vt,
                                                   bf16* __restrict__ O) {
    __shared__ bf16 lds[40960];   // 2 x (Ks[64][128] | Vs[128][64]) | pbuf 4 x [32][64] = 80 KiB

    const int flat = blockIdx.x;
    const int x = flat & 7;
    const int j = flat >> 3;
    const int hkb = x * 2 + (j & 1);
    const int qt = 63 - (j >> 1);
    const int hk = hkb & 7, b = hkb >> 3;
    const int q0 = qt * 32;

    const int tid = threadIdx.x;
    const int w = tid >> 6, lane = tid & 63;
    const int lg = lane >> 4, lr = lane & 15;
    const int h = hk * 4 + w;
    bf16* pb = lds + 32768 + w * 2048;

    const bf16* qbase = Q + ((size_t)(b * S_ + q0 + lr)) * (H_ * HD_) + h * HD_ + lg * 8;
    bf16x8 qf[2][4];
    #pragma unroll
    for (int m = 0; m < 2; m++)
        #pragma unroll
        for (int kk = 0; kk < 4; kk++)
            qf[m][kk] = *(const bf16x8*)(qbase + (size_t)m * 16 * (H_ * HD_) + kk * 32);

    const bf16* Kh = Kb + ((size_t)b * S_) * (HKV_ * HD_) + hk * HD_;
    const bf16* Vh = Vt + ((size_t)(b * HKV_ + hk)) * HD_ * S_;

    const int krow_s  = tid >> 4;
    const int kchnk_s = (tid & 15) ^ (tid >> 4);
    const int vrow_s  = tid >> 3;
    const int vchnk_s = (tid & 7) ^ ((tid >> 3) & 7);

    // stage K [64][128] (chunk ^= k&15) and V^T [128][64] (chunk ^= d&7) into buf
    auto stage = [&](int buf, int k0) {
        bf16* Kd = lds + buf * 16384;
        bf16* Vd = Kd + 8192;
        #pragma unroll
        for (int jj = 0; jj < 4; jj++)
            gload_lds16(Kh + (size_t)(k0 + jj * 16 + krow_s) * (HKV_ * HD_) + kchnk_s * 8,
                        Kd + jj * 2048 + tid * 8);
        #pragma unroll
        for (int jj = 0; jj < 4; jj++)
            gload_lds16(Vh + (size_t)(jj * 32 + vrow_s) * S_ + k0 + vchnk_s * 8,
                        Vd + jj * 2048 + tid * 8);
    };

    f32x4 acc[2][8];
    #pragma unroll
    for (int m = 0; m < 2; m++)
        #pragma unroll
        for (int dt = 0; dt < 8; dt++)
            acc[m][dt] = (f32x4){0.f, 0.f, 0.f, 0.f};
    float rowmax[2][4], rowsum[2][4];
    #pragma unroll
    for (int m = 0; m < 2; m++)
        #pragma unroll
        for (int r = 0; r < 4; r++) { rowmax[m][r] = -1e30f; rowsum[m][r] = 0.f; }

    const float scale = 0.08838834764831845f;
    const int nt = (q0 + 32 + KVB_ - 1) / KVB_;

    // prologue: stage tile 0, wait, sync
    stage(0, 0);
    asm volatile("s_waitcnt vmcnt(0)" ::: "memory");
    __syncthreads();

    for (int it = 0; it < nt; ++it) {
        const int cur = it & 1;
        const bf16* Ks = lds + cur * 16384;
        const bf16* Vs = Ks + 8192;

        // issue next tile's loads first (overlap with this tile's compute)
        if (it + 1 < nt) stage(cur ^ 1, (it + 1) * KVB_);

        f32x4 st[2][4];
        #pragma unroll
        for (int m = 0; m < 2; m++)
            #pragma unroll
            for (int kt = 0; kt < 4; kt++)
                st[m][kt] = (f32x4){0.f, 0.f, 0.f, 0.f};
        #pragma unroll
        for (int kt = 0; kt < 4; kt++) {
            bf16x8 kf[4];
            #pragma unroll
            for (int kk = 0; kk < 4; kk++)
                kf[kk] = *(const bf16x8*)(Ks + (kt * 16 + lr) * 128 + (((kk * 4 + lg) ^ lr) << 3));
            #pragma unroll
            for (int m = 0; m < 2; m++)
                #pragma unroll
                for (int kk = 0; kk < 4; kk++)
                    st[m][kt] = __builtin_amdgcn_mfma_f32_16x16x32_bf16(qf[m][kk], kf[kk], st[m][kt], 0, 0, 0);
        }

        const int k0 = it * KVB_;
        const bool need_mask = (k0 + KVB_ - 1 > q0);
        #pragma unroll
        for (int m = 0; m < 2; m++)
            #pragma unroll
            for (int kt = 0; kt < 4; kt++)
                #pragma unroll
                for (int r = 0; r < 4; r++) {
                    float s = st[m][kt][r] * scale;
                    if (need_mask) {
                        const int qg = q0 + m * 16 + lg * 4 + r;
                        const int kg = k0 + kt * 16 + lr;
                        s = (kg <= qg) ? s : -1e30f;
                    }
                    st[m][kt][r] = s;
                }

        float vmax[2][4];
        #pragma unroll
        for (int m = 0; m < 2; m++)
            #pragma unroll
            for (int r = 0; r < 4; r++) {
                float v = fmaxf(fmaxf(st[m][0][r], st[m][1][r]), fmaxf(st[m][2][r], st[m][3][r]));
                v = fmaxf(v, __shfl_xor(v, 1));
                v = fmaxf(v, __shfl_xor(v, 2));
                v = fmaxf(v, __shfl_xor(v, 4));
                v = fmaxf(v, __shfl_xor(v, 8));
                vmax[m][r] = v;
            }
        bool upd = false;
        #pragma unroll
        for (int m = 0; m < 2; m++)
            #pragma unroll
            for (int r = 0; r < 4; r++)
                upd |= (vmax[m][r] > rowmax[m][r] + 8.0f);
        if (__any(upd)) {
            #pragma unroll
            for (int m = 0; m < 2; m++)
                #pragma unroll
                for (int r = 0; r < 4; r++) {
                    const float mn = fmaxf(rowmax[m][r], vmax[m][r]);
                    const float fac = __expf(rowmax[m][r] - mn);
                    rowmax[m][r] = mn;
                    rowsum[m][r] *= fac;
                    #pragma unroll
                    for (int dt = 0; dt < 8; dt++)
                        acc[m][dt][r] *= fac;
                }
        }
        #pragma unroll
        for (int m = 0; m < 2; m++)
            #pragma unroll
            for (int r = 0; r < 4; r++) {
                float ssum = 0.f;
                #pragma unroll
                for (int kt = 0; kt < 4; kt++) {
                    const float p = __expf(st[m][kt][r] - rowmax[m][r]);
                    st[m][kt][r] = p;
                    ssum += p;
                }
                ssum += __shfl_xor(ssum, 1);
                ssum += __shfl_xor(ssum, 2);
                ssum += __shfl_xor(ssum, 4);
                ssum += __shfl_xor(ssum, 8);
                rowsum[m][r] += ssum;
            }

        #pragma unroll
        for (int m = 0; m < 2; m++)
            #pragma unroll
            for (int kt = 0; kt < 4; kt++)
                #pragma unroll
                for (int r = 0; r < 4; r++) {
                    const int row = m * 16 + lg * 4 + r;
                    pb[(row * 64 + kt * 16 + lr) ^ ((row & 7) << 3)] = (bf16)st[m][kt][r];
                }

        bf16x8 pf[2][2];
        #pragma unroll
        for (int m = 0; m < 2; m++)
            #pragma unroll
            for (int ks = 0; ks < 2; ks++)
                pf[m][ks] = *(const bf16x8*)(pb + (m * 16 + lr) * 64 + ((ks * 32 + lg * 8) ^ ((lr & 7) << 3)));
        #pragma unroll
        for (int dt = 0; dt < 8; dt++) {
            bf16x8 vf[2];
            #pragma unroll
            for (int ks = 0; ks < 2; ks++)
                vf[ks] = *(const bf16x8*)(Vs + (dt * 16 + lr) * 64 + (((ks * 4 + lg) ^ (lr & 7)) << 3));
            #pragma unroll
            for (int m = 0; m < 2; m++)
                #pragma unroll
                for (int ks = 0; ks < 2; ks++)
                    acc[m][dt] = __builtin_amdgcn_mfma_f32_16x16x32_bf16(pf[m][ks], vf[ks], acc[m][dt], 0, 0, 0);
        }

        // next tile's loads have had all of compute to land; drain is ~free
        asm volatile("s_waitcnt vmcnt(0)" ::: "memory");
        __syncthreads();
    }

    #pragma unroll
    for (int m = 0; m < 2; m++) {
        float inv[4];
        #pragma unroll
        for (int r = 0; r < 4; r++) inv[r] = 1.0f / rowsum[m][r];
        #pragma unroll
        for (int dt = 0; dt < 8; dt++)
            #pragma unroll
            for (int r = 0; r < 4; r++) {
                const size_t row = (size_t)(b * S_ + q0 + m * 16 + lg * 4 + r);
                O[row * (H_ * HD_) + h * HD_ + dt * 16 + lr] = (bf16)(acc[m][dt][r] * inv[r]);
            }
    }
}

// ---------------- launch ----------------

extern "C" void kernel_launch(void* const* d_in, const int* in_sizes, int n_in,
                              void* d_out, int out_size, void* d_ws, size_t ws_size,
                              hipStream_t stream) {
    const float* x  = (const float*)d_in[0];
    const float* Wq = (const float*)d_in[1];
    const float* Wk = (const float*)d_in[2];
    const float* Wv = (const float*)d_in[3];
    const float* Wo = (const float*)d_in[4];
    float* out = (float*)d_out;

    const size_t NX  = (size_t)B_ * S_ * D_;
    const size_t NWQ = (size_t)D_ * H_ * HD_;
    const size_t NWK = (size_t)D_ * HKV_ * HD_;

    bf16* p = (bf16*)d_ws;
    bf16* xb  = p;  p += NX;
    bf16* WqT = p;  p += NWQ;
    bf16* WkT = p;  p += NWK;
    bf16* WvT = p;  p += NWK;
    bf16* Qb  = p;  p += NX;
    bf16* Kbuf= p;  p += NWK;
    bf16* Vb  = p;  p += NWK;
    bf16* Vtb = WkT;
    bf16* Ab  = xb;
    bf16* WoT = WqT;

    // prep
    cast_f32_bf16_kernel<<<(int)(NX / 1024), 256, 0, stream>>>(x, xb, (int)NX);
    transpose_cast_kernel<<<dim3((H_ * HD_) / 32, D_ / 32), dim3(32, 8), 0, stream>>>(Wq, WqT, D_, H_ * HD_);
    transpose_cast_kernel<<<dim3((HKV_ * HD_) / 32, D_ / 32), dim3(32, 8), 0, stream>>>(Wk, WkT, D_, HKV_ * HD_);
    transpose_cast_kernel<<<dim3((HKV_ * HD_) / 32, D_ / 32), dim3(32, 8), 0, stream>>>(Wv, WvT, D_, HKV_ * HD_);

    // projections: 256^2 8-phase for the two 4096x4096 GEMMs; 128^2 for K/V
    gemm_bt256_kernel<bf16><<<256, 512, 0, stream>>>(xb, WqT, Qb, B_ * S_, H_ * HD_, D_);
    gemm_bt_kernel<bf16><<<dim3(32, 8), 256, 0, stream>>>(xb, WkT, Kbuf, B_ * S_, HKV_ * HD_, D_);
    gemm_bt_kernel<bf16><<<dim3(32, 8), 256, 0, stream>>>(xb, WvT, Vb,   B_ * S_, HKV_ * HD_, D_);

    // rope
    rope_kernel<<<B_ * S_, 256, 0, stream>>>(Qb, H_);
    rope_kernel<<<B_ * S_, 256, 0, stream>>>(Kbuf, HKV_);

    // V transpose
    transpose_v_kernel<<<dim3(HD_ / 32, S_ / 32, B_ * HKV_), dim3(32, 8), 0, stream>>>(Vb, Vtb);

    // attention: 1024 blocks x 256 threads (XCD-swizzled, descending-work order)
    attn_kernel<<<1024, 256, 0, stream>>>(Qb, Kbuf, Vtb, Ab);

    // output projection
    transpose_cast_kernel<<<dim3(D_ / 32, (H_ * HD_) / 32), dim3(32, 8), 0, stream>>>(Wo, WoT, H_ * HD_, D_);
    gemm_bt256_kernel<float><<<256, 512, 0, stream>>>(Ab, WoT, out, B_ * S_, D_, H_ * HD_);
}

// Round 10
// 707.437 us; speedup vs baseline: 1.0823x; 1.0823x over previous
//
#include <hip/hip_runtime.h>
#include <hip/hip_bf16.h>

// Problem constants
#define B_   2
#define S_   2048
#define D_   4096
#define H_   32
#define HKV_ 8
#define HD_  128
#define QKVS 6144   // fused QKV row stride (H*HD + 2*HKV*HD)

typedef __bf16 bf16;
typedef __bf16 bf16x8 __attribute__((ext_vector_type(8)));
typedef __bf16 bf16x4 __attribute__((ext_vector_type(4)));
typedef float  f32x4  __attribute__((ext_vector_type(4)));

// ---------------- prep kernels ----------------

__global__ void cast_f32_bf16_kernel(const float* __restrict__ in, bf16* __restrict__ out, int n) {
    int i = (blockIdx.x * blockDim.x + threadIdx.x) * 4;
    if (i >= n) return;
    const float4 v = *(const float4*)(in + i);
    bf16x4 o;
    o[0] = (bf16)v.x; o[1] = (bf16)v.y; o[2] = (bf16)v.z; o[3] = (bf16)v.w;
    *(bf16x4*)(out + i) = o;
}

// W: K x N fp32 row-major  ->  WT: N x K bf16 row-major
__global__ void transpose_cast_kernel(const float* __restrict__ W, bf16* __restrict__ WT, int K, int N) {
    __shared__ float t[32][33];
    const int n0 = blockIdx.x * 32, k0 = blockIdx.y * 32;
    const int tx = threadIdx.x, ty = threadIdx.y;
    #pragma unroll
    for (int i = ty; i < 32; i += 8) t[i][tx] = W[(size_t)(k0 + i) * N + n0 + tx];
    __syncthreads();
    #pragma unroll
    for (int i = ty; i < 32; i += 8) WT[(size_t)(n0 + i) * K + k0 + tx] = (bf16)t[tx][i];
}

// V (cols 5120.. of QKV, row stride QKVS) -> Vt: (b,hk,d) x s bf16
__global__ void transpose_v_kernel(const bf16* __restrict__ V, bf16* __restrict__ Vt) {
    __shared__ bf16 t[32][33];
    const int bh = blockIdx.z;            // b*HKV + hk
    const int b = bh >> 3, hk = bh & 7;
    const int d0 = blockIdx.x * 32, s0 = blockIdx.y * 32;
    const int tx = threadIdx.x, ty = threadIdx.y;
    #pragma unroll
    for (int i = ty; i < 32; i += 8)
        t[i][tx] = V[((size_t)(b * S_ + s0 + i)) * QKVS + hk * HD_ + d0 + tx];
    __syncthreads();
    #pragma unroll
    for (int i = ty; i < 32; i += 8)
        Vt[((size_t)(bh * HD_ + d0 + i)) * S_ + s0 + tx] = t[tx][i];
}

// rotate-half RoPE in place on rows of a strided matrix, pos = row % S
__global__ void rope_kernel(bf16* __restrict__ T, int nh, int stride) {
    const int row = blockIdx.x;
    const int pos = row & (S_ - 1);
    const size_t base = (size_t)row * stride;
    const int npairs = nh * 64;
    const float c = 13.287712379549449f / 64.0f;   // log2(10000)/64
    for (int p = threadIdx.x; p < npairs; p += blockDim.x) {
        const int h = p >> 6, d = p & 63;
        const float invf = exp2f(-(float)d * c);
        const float ang = (float)pos * invf;
        float sn, cs;
        sincosf(ang, &sn, &cs);
        const size_t i1 = base + (size_t)h * HD_ + d;
        const size_t i2 = i1 + 64;
        const float a  = (float)T[i1];
        const float b2 = (float)T[i2];
        T[i1] = (bf16)(a * cs - b2 * sn);
        T[i2] = (bf16)(b2 * cs + a * sn);
    }
}

__device__ __forceinline__ void gload_lds16(const bf16* g, bf16* l) {
    __builtin_amdgcn_global_load_lds((const __attribute__((address_space(1))) void*)g,
                                     (__attribute__((address_space(3))) void*)l, 16, 0, 0);
}

// ---------------- GEMM 256x256, BK=64, 8 waves, 8-phase pipelined (m201 structure) ----------------

#define PHASE256(QM, QN, STAGE_STMT, DO_VM)                                              \
    {                                                                                    \
        bf16x8 af[4][2], bfr[2][2];                                                      \
        _Pragma("unroll") for (int i = 0; i < 4; ++i) {                                  \
            const int row = wm * 128 + (QM * 4 + i) * 16 + lr;                           \
            _Pragma("unroll") for (int kk = 0; kk < 2; ++kk)                             \
                af[i][kk] = *(const bf16x8*)(curA + row * 64 + (((kk * 4 + lg) ^ (lr & 7)) << 3)); \
        }                                                                                \
        _Pragma("unroll") for (int i2 = 0; i2 < 2; ++i2) {                               \
            const int row = wn * 64 + (QN * 2 + i2) * 16 + lr;                           \
            _Pragma("unroll") for (int kk = 0; kk < 2; ++kk)                             \
                bfr[i2][kk] = *(const bf16x8*)(curB + row * 64 + (((kk * 4 + lg) ^ (lr & 7)) << 3)); \
        }                                                                                \
        STAGE_STMT;                                                                      \
        if (DO_VM) asm volatile("s_waitcnt vmcnt(4)" ::: "memory");                      \
        __builtin_amdgcn_s_barrier();                                                    \
        asm volatile("s_waitcnt lgkmcnt(0)" ::: "memory");                               \
        __builtin_amdgcn_sched_barrier(0);                                               \
        __builtin_amdgcn_s_setprio(1);                                                   \
        _Pragma("unroll") for (int i = 0; i < 4; ++i)                                    \
            _Pragma("unroll") for (int i2 = 0; i2 < 2; ++i2)                             \
                _Pragma("unroll") for (int kk = 0; kk < 2; ++kk)                         \
                    acc[QM * 4 + i][QN * 2 + i2] = __builtin_amdgcn_mfma_f32_16x16x32_bf16( \
                        af[i][kk], bfr[i2][kk], acc[QM * 4 + i][QN * 2 + i2], 0, 0, 0);  \
        __builtin_amdgcn_s_setprio(0);                                                   \
        __builtin_amdgcn_s_barrier();                                                    \
    }

template <typename CT>
__global__ __launch_bounds__(512, 2) void gemm_bt256_kernel(const bf16* __restrict__ A,
                                                            const bf16* __restrict__ Bm,
                                                            CT* __restrict__ C,
                                                            int M, int N, int K) {
    __shared__ bf16 sm[65536];   // 128 KiB
    const int nbx = N >> 8;
    const int cpx = gridDim.x >> 3;
    const int bid = blockIdx.x;
    const int swz = (bid & 7) * cpx + (bid >> 3);       // XCD swizzle (grid % 8 == 0)
    const int m0 = (swz / nbx) << 8;
    const int n0 = (swz % nbx) << 8;

    const int tid = threadIdx.x;
    const int w = tid >> 6, lane = tid & 63;
    const int wm = w >> 2, wn = w & 3;                  // 2 x 4 wave grid, 128x64 per wave
    const int lg = lane >> 4, lr = lane & 15;
    const int nkt = K >> 6;

    const bf16* Ab = A + (size_t)m0 * K;
    const bf16* Bb = Bm + (size_t)n0 * K;

    const int u8 = tid >> 3;
    const int schunk = ((tid & 7) ^ (u8 & 7)) << 3;     // pre-swizzled source col offset

    auto stageA = [&](int buf, int kt, int h) {
        bf16* dst = sm + buf * 32768 + h * 4096 + tid * 8;
        const bf16* src = Ab + (size_t)(h * 64 + u8) * K + kt * 64 + schunk;
        gload_lds16(src, dst);
        gload_lds16(src + (size_t)128 * K, dst + 8192);
    };
    auto stageB = [&](int buf, int kt, int h) {
        bf16* dst = sm + buf * 32768 + 16384 + h * 2048 + ((u8 >> 5) << 12) + ((u8 & 31) << 6) + ((tid & 7) << 3);
        const bf16* src = Bb + (size_t)(h * 32 + ((u8 >> 5) << 6) + (u8 & 31)) * K + kt * 64 + schunk;
        gload_lds16(src, dst);
        gload_lds16(src + (size_t)128 * K, dst + 8192);
    };

    f32x4 acc[8][4] = {};

    // prologue: tile0 fully -> buf0 (8 loads); tile1 B0,A0 -> buf1 (4 loads)
    stageA(0, 0, 0); stageA(0, 0, 1); stageB(0, 0, 0); stageB(0, 0, 1);
    stageB(1, 1, 0); stageA(1, 1, 0);
    asm volatile("s_waitcnt vmcnt(4)" ::: "memory");    // tile0 landed; tile1's 4 in flight
    __builtin_amdgcn_s_barrier();

    for (int t = 0; t < nkt; ++t) {
        const int cur = t & 1;
        const bf16* curA = sm + cur * 32768;
        const bf16* curB = curA + 16384;
        PHASE256(0, 0, { if (t + 1 < nkt) stageA(cur ^ 1, t + 1, 1); }, 0)
        PHASE256(1, 0, { if (t + 1 < nkt) stageB(cur ^ 1, t + 1, 1); }, 0)
        PHASE256(0, 1, { if (t + 2 < nkt) stageB(cur, t + 2, 0); }, 0)
        PHASE256(1, 1, { if (t + 2 < nkt) stageA(cur, t + 2, 0); }, 1)
    }

    #pragma unroll
    for (int mi = 0; mi < 8; ++mi)
        #pragma unroll
        for (int ni = 0; ni < 4; ++ni)
            #pragma unroll
            for (int r = 0; r < 4; ++r) {
                const int row = m0 + wm * 128 + mi * 16 + lg * 4 + r;
                const int col = n0 + wn * 64 + ni * 16 + lr;
                C[(size_t)row * N + col] = (CT)acc[mi][ni][r];
            }
}

// ---------------- flash attention (causal, GQA) ----------------
// Block = 256 threads = 4 waves = 4 q-heads of one GQA group, same 32 q-rows.
// Q and K live in the fused QKV buffer (row stride QKVS); Vt is [d][s].
#define KVB_ 64

__global__ __launch_bounds__(256) void attn_kernel(const bf16* __restrict__ Q,
                                                   const bf16* __restrict__ Kb,
                                                   const bf16* __restrict__ Vt,
                                                   bf16* __restrict__ O) {
    __shared__ bf16 lds[24576];   // Ks[64][128] | Vs[128][64] | pbuf 4 x [32][64]
    bf16* Ks = lds;
    bf16* Vs = lds + 8192;

    const int flat = blockIdx.x;
    const int x = flat & 7;
    const int j = flat >> 3;
    const int hkb = x * 2 + (j & 1);
    const int qt = 63 - (j >> 1);
    const int hk = hkb & 7, b = hkb >> 3;
    const int q0 = qt * 32;

    const int tid = threadIdx.x;
    const int w = tid >> 6, lane = tid & 63;
    const int lg = lane >> 4, lr = lane & 15;
    const int h = hk * 4 + w;
    bf16* pb = lds + 16384 + w * 2048;

    const bf16* qbase = Q + ((size_t)(b * S_ + q0 + lr)) * QKVS + h * HD_ + lg * 8;
    bf16x8 qf[2][4];
    #pragma unroll
    for (int m = 0; m < 2; m++)
        #pragma unroll
        for (int kk = 0; kk < 4; kk++)
            qf[m][kk] = *(const bf16x8*)(qbase + (size_t)m * 16 * QKVS + kk * 32);

    const bf16* Kh = Kb + ((size_t)b * S_) * QKVS + hk * HD_;
    const bf16* Vh = Vt + ((size_t)(b * HKV_ + hk)) * HD_ * S_;

    const int krow_s  = tid >> 4;
    const int kchnk_s = (tid & 15) ^ (tid >> 4);
    const int vrow_s  = tid >> 3;
    const int vchnk_s = (tid & 7) ^ ((tid >> 3) & 7);

    f32x4 acc[2][8];
    #pragma unroll
    for (int m = 0; m < 2; m++)
        #pragma unroll
        for (int dt = 0; dt < 8; dt++)
            acc[m][dt] = (f32x4){0.f, 0.f, 0.f, 0.f};
    float rowmax[2][4], rowsum[2][4];
    #pragma unroll
    for (int m = 0; m < 2; m++)
        #pragma unroll
        for (int r = 0; r < 4; r++) { rowmax[m][r] = -1e30f; rowsum[m][r] = 0.f; }

    const float scale = 0.08838834764831845f;
    const int nt = (q0 + 32 + KVB_ - 1) / KVB_;

    for (int it = 0; it < nt; ++it) {
        const int k0 = it * KVB_;
        #pragma unroll
        for (int jj = 0; jj < 4; jj++)
            gload_lds16(Kh + (size_t)(k0 + jj * 16 + krow_s) * QKVS + kchnk_s * 8,
                        Ks + jj * 2048 + tid * 8);
        #pragma unroll
        for (int jj = 0; jj < 4; jj++)
            gload_lds16(Vh + (size_t)(jj * 32 + vrow_s) * S_ + k0 + vchnk_s * 8,
                        Vs + jj * 2048 + tid * 8);
        __syncthreads();

        f32x4 st[2][4];
        #pragma unroll
        for (int m = 0; m < 2; m++)
            #pragma unroll
            for (int kt = 0; kt < 4; kt++)
                st[m][kt] = (f32x4){0.f, 0.f, 0.f, 0.f};
        #pragma unroll
        for (int kt = 0; kt < 4; kt++) {
            bf16x8 kf[4];
            #pragma unroll
            for (int kk = 0; kk < 4; kk++)
                kf[kk] = *(const bf16x8*)(Ks + (kt * 16 + lr) * 128 + (((kk * 4 + lg) ^ lr) << 3));
            #pragma unroll
            for (int m = 0; m < 2; m++)
                #pragma unroll
                for (int kk = 0; kk < 4; kk++)
                    st[m][kt] = __builtin_amdgcn_mfma_f32_16x16x32_bf16(qf[m][kk], kf[kk], st[m][kt], 0, 0, 0);
        }

        const bool need_mask = (k0 + KVB_ - 1 > q0);
        #pragma unroll
        for (int m = 0; m < 2; m++)
            #pragma unroll
            for (int kt = 0; kt < 4; kt++)
                #pragma unroll
                for (int r = 0; r < 4; r++) {
                    float s = st[m][kt][r] * scale;
                    if (need_mask) {
                        const int qg = q0 + m * 16 + lg * 4 + r;
                        const int kg = k0 + kt * 16 + lr;
                        s = (kg <= qg) ? s : -1e30f;
                    }
                    st[m][kt][r] = s;
                }

        float vmax[2][4];
        #pragma unroll
        for (int m = 0; m < 2; m++)
            #pragma unroll
            for (int r = 0; r < 4; r++) {
                float v = fmaxf(fmaxf(st[m][0][r], st[m][1][r]), fmaxf(st[m][2][r], st[m][3][r]));
                v = fmaxf(v, __shfl_xor(v, 1));
                v = fmaxf(v, __shfl_xor(v, 2));
                v = fmaxf(v, __shfl_xor(v, 4));
                v = fmaxf(v, __shfl_xor(v, 8));
                vmax[m][r] = v;
            }
        bool upd = false;
        #pragma unroll
        for (int m = 0; m < 2; m++)
            #pragma unroll
            for (int r = 0; r < 4; r++)
                upd |= (vmax[m][r] > rowmax[m][r] + 8.0f);
        if (__any(upd)) {
            #pragma unroll
            for (int m = 0; m < 2; m++)
                #pragma unroll
                for (int r = 0; r < 4; r++) {
                    const float mn = fmaxf(rowmax[m][r], vmax[m][r]);
                    const float fac = __expf(rowmax[m][r] - mn);
                    rowmax[m][r] = mn;
                    rowsum[m][r] *= fac;
                    #pragma unroll
                    for (int dt = 0; dt < 8; dt++)
                        acc[m][dt][r] *= fac;
                }
        }
        #pragma unroll
        for (int m = 0; m < 2; m++)
            #pragma unroll
            for (int r = 0; r < 4; r++) {
                float ssum = 0.f;
                #pragma unroll
                for (int kt = 0; kt < 4; kt++) {
                    const float p = __expf(st[m][kt][r] - rowmax[m][r]);
                    st[m][kt][r] = p;
                    ssum += p;
                }
                ssum += __shfl_xor(ssum, 1);
                ssum += __shfl_xor(ssum, 2);
                ssum += __shfl_xor(ssum, 4);
                ssum += __shfl_xor(ssum, 8);
                rowsum[m][r] += ssum;
            }

        #pragma unroll
        for (int m = 0; m < 2; m++)
            #pragma unroll
            for (int kt = 0; kt < 4; kt++)
                #pragma unroll
                for (int r = 0; r < 4; r++) {
                    const int row = m * 16 + lg * 4 + r;
                    pb[(row * 64 + kt * 16 + lr) ^ ((row & 7) << 3)] = (bf16)st[m][kt][r];
                }

        bf16x8 pf[2][2];
        #pragma unroll
        for (int m = 0; m < 2; m++)
            #pragma unroll
            for (int ks = 0; ks < 2; ks++)
                pf[m][ks] = *(const bf16x8*)(pb + (m * 16 + lr) * 64 + ((ks * 32 + lg * 8) ^ ((lr & 7) << 3)));
        #pragma unroll
        for (int dt = 0; dt < 8; dt++) {
            bf16x8 vf[2];
            #pragma unroll
            for (int ks = 0; ks < 2; ks++)
                vf[ks] = *(const bf16x8*)(Vs + (dt * 16 + lr) * 64 + (((ks * 4 + lg) ^ (lr & 7)) << 3));
            #pragma unroll
            for (int m = 0; m < 2; m++)
                #pragma unroll
                for (int ks = 0; ks < 2; ks++)
                    acc[m][dt] = __builtin_amdgcn_mfma_f32_16x16x32_bf16(pf[m][ks], vf[ks], acc[m][dt], 0, 0, 0);
        }
        __syncthreads();
    }

    #pragma unroll
    for (int m = 0; m < 2; m++) {
        float inv[4];
        #pragma unroll
        for (int r = 0; r < 4; r++) inv[r] = 1.0f / rowsum[m][r];
        #pragma unroll
        for (int dt = 0; dt < 8; dt++)
            #pragma unroll
            for (int r = 0; r < 4; r++) {
                const size_t row = (size_t)(b * S_ + q0 + m * 16 + lg * 4 + r);
                O[row * (H_ * HD_) + h * HD_ + dt * 16 + lr] = (bf16)(acc[m][dt][r] * inv[r]);
            }
    }
}

// ---------------- launch ----------------

extern "C" void kernel_launch(void* const* d_in, const int* in_sizes, int n_in,
                              void* d_out, int out_size, void* d_ws, size_t ws_size,
                              hipStream_t stream) {
    const float* x  = (const float*)d_in[0];
    const float* Wq = (const float*)d_in[1];
    const float* Wk = (const float*)d_in[2];
    const float* Wv = (const float*)d_in[3];
    const float* Wo = (const float*)d_in[4];
    float* out = (float*)d_out;

    const size_t NX   = (size_t)B_ * S_ * D_;         // 16.78M elems
    const size_t NQKVW= (size_t)QKVS * D_;            // 25.2M elems (WqkvT)
    const size_t NQKV = (size_t)B_ * S_ * QKVS;       // 25.2M elems (QKV acts)
    const size_t NWK  = (size_t)D_ * HKV_ * HD_;      // 4.19M elems

    bf16* p = (bf16*)d_ws;
    bf16* xb    = p;  p += NX;       // x bf16; reused as attention output
    bf16* WqkvT = p;  p += NQKVW;    // [6144][4096]; reused as Vtb + WoT
    bf16* QKV   = p;  p += NQKV;     // [B*S][6144]
    bf16* Ab  = xb;                  // alias (xb dead after QKV GEMM)
    bf16* Vtb = WqkvT;               // alias (WqkvT dead after QKV GEMM), 4.19M elems
    bf16* WoT = WqkvT + NWK;         // alias, 16.78M elems

    // prep: cast x; build WqkvT = [WqT; WkT; WvT]
    cast_f32_bf16_kernel<<<(int)(NX / 1024), 256, 0, stream>>>(x, xb, (int)NX);
    transpose_cast_kernel<<<dim3((H_ * HD_) / 32, D_ / 32), dim3(32, 8), 0, stream>>>(Wq, WqkvT, D_, H_ * HD_);
    transpose_cast_kernel<<<dim3((HKV_ * HD_) / 32, D_ / 32), dim3(32, 8), 0, stream>>>(Wk, WqkvT + (size_t)(H_ * HD_) * D_, D_, HKV_ * HD_);
    transpose_cast_kernel<<<dim3((HKV_ * HD_) / 32, D_ / 32), dim3(32, 8), 0, stream>>>(Wv, WqkvT + (size_t)(H_ * HD_ + HKV_ * HD_) * D_, D_, HKV_ * HD_);

    // fused QKV projection: M=4096, N=6144, K=4096 (384 blocks, %8==0)
    gemm_bt256_kernel<bf16><<<384, 512, 0, stream>>>(xb, WqkvT, QKV, B_ * S_, QKVS, D_);

    // rope on Q (cols 0..4095) and K (cols 4096..5119)
    rope_kernel<<<B_ * S_, 256, 0, stream>>>(QKV, H_, QKVS);
    rope_kernel<<<B_ * S_, 256, 0, stream>>>(QKV + H_ * HD_, HKV_, QKVS);

    // V transpose (V = cols 5120.. of QKV)
    transpose_v_kernel<<<dim3(HD_ / 32, S_ / 32, B_ * HKV_), dim3(32, 8), 0, stream>>>(QKV + H_ * HD_ + HKV_ * HD_, Vtb);

    // attention: Q at QKV col 0, K at col 4096; both stride QKVS
    attn_kernel<<<1024, 256, 0, stream>>>(QKV, QKV + H_ * HD_, Vtb, Ab);

    // output projection
    transpose_cast_kernel<<<dim3(D_ / 32, (H_ * HD_) / 32), dim3(32, 8), 0, stream>>>(Wo, WoT, H_ * HD_, D_);
    gemm_bt256_kernel<float><<<256, 512, 0, stream>>>(Ab, WoT, out, B_ * S_, D_, H_ * HD_);
}

// Round 11
// 659.106 us; speedup vs baseline: 1.1616x; 1.0733x over previous
//
#include <hip/hip_runtime.h>
#include <hip/hip_bf16.h>

// Problem constants
#define B_   2
#define S_   2048
#define D_   4096
#define H_   32
#define HKV_ 8
#define HD_  128
#define QKVS 6144   // fused QKV row stride (H*HD + 2*HKV*HD)

typedef __bf16 bf16;
typedef __bf16 bf16x8 __attribute__((ext_vector_type(8)));
typedef __bf16 bf16x4 __attribute__((ext_vector_type(4)));
typedef float  f32x4  __attribute__((ext_vector_type(4)));

// ---------------- prep kernels ----------------

__global__ void cast_f32_bf16_kernel(const float* __restrict__ in, bf16* __restrict__ out, int n) {
    int i = (blockIdx.x * blockDim.x + threadIdx.x) * 4;
    if (i >= n) return;
    const float4 v = *(const float4*)(in + i);
    bf16x4 o;
    o[0] = (bf16)v.x; o[1] = (bf16)v.y; o[2] = (bf16)v.z; o[3] = (bf16)v.w;
    *(bf16x4*)(out + i) = o;
}

// W: K x N fp32 row-major  ->  WT: N x K bf16 row-major
__global__ void transpose_cast_kernel(const float* __restrict__ W, bf16* __restrict__ WT, int K, int N) {
    __shared__ float t[32][33];
    const int n0 = blockIdx.x * 32, k0 = blockIdx.y * 32;
    const int tx = threadIdx.x, ty = threadIdx.y;
    #pragma unroll
    for (int i = ty; i < 32; i += 8) t[i][tx] = W[(size_t)(k0 + i) * N + n0 + tx];
    __syncthreads();
    #pragma unroll
    for (int i = ty; i < 32; i += 8) WT[(size_t)(n0 + i) * K + k0 + tx] = (bf16)t[tx][i];
}

// V (cols 5120.. of QKV, row stride QKVS) -> Vt: (b,hk,d) x s bf16
__global__ void transpose_v_kernel(const bf16* __restrict__ V, bf16* __restrict__ Vt) {
    __shared__ bf16 t[32][33];
    const int bh = blockIdx.z;            // b*HKV + hk
    const int b = bh >> 3, hk = bh & 7;
    const int d0 = blockIdx.x * 32, s0 = blockIdx.y * 32;
    const int tx = threadIdx.x, ty = threadIdx.y;
    #pragma unroll
    for (int i = ty; i < 32; i += 8)
        t[i][tx] = V[((size_t)(b * S_ + s0 + i)) * QKVS + hk * HD_ + d0 + tx];
    __syncthreads();
    #pragma unroll
    for (int i = ty; i < 32; i += 8)
        Vt[((size_t)(bh * HD_ + d0 + i)) * S_ + s0 + tx] = t[tx][i];
}

// rotate-half RoPE in place on rows of a strided matrix, pos = row % S
__global__ void rope_kernel(bf16* __restrict__ T, int nh, int stride) {
    const int row = blockIdx.x;
    const int pos = row & (S_ - 1);
    const size_t base = (size_t)row * stride;
    const int npairs = nh * 64;
    const float c = 13.287712379549449f / 64.0f;   // log2(10000)/64
    for (int p = threadIdx.x; p < npairs; p += blockDim.x) {
        const int h = p >> 6, d = p & 63;
        const float invf = exp2f(-(float)d * c);
        const float ang = (float)pos * invf;
        float sn, cs;
        sincosf(ang, &sn, &cs);
        const size_t i1 = base + (size_t)h * HD_ + d;
        const size_t i2 = i1 + 64;
        const float a  = (float)T[i1];
        const float b2 = (float)T[i2];
        T[i1] = (bf16)(a * cs - b2 * sn);
        T[i2] = (bf16)(b2 * cs + a * sn);
    }
}

__device__ __forceinline__ void gload_lds16(const bf16* g, bf16* l) {
    __builtin_amdgcn_global_load_lds((const __attribute__((address_space(1))) void*)g,
                                     (__attribute__((address_space(3))) void*)l, 16, 0, 0);
}

// ---------------- GEMM 256x256, BK=64, 8 waves, 8-phase pipelined (m201 structure) ----------------

#define PHASE256(QM, QN, STAGE_STMT, DO_VM)                                              \
    {                                                                                    \
        bf16x8 af[4][2], bfr[2][2];                                                      \
        _Pragma("unroll") for (int i = 0; i < 4; ++i) {                                  \
            const int row = wm * 128 + (QM * 4 + i) * 16 + lr;                           \
            _Pragma("unroll") for (int kk = 0; kk < 2; ++kk)                             \
                af[i][kk] = *(const bf16x8*)(curA + row * 64 + (((kk * 4 + lg) ^ (lr & 7)) << 3)); \
        }                                                                                \
        _Pragma("unroll") for (int i2 = 0; i2 < 2; ++i2) {                               \
            const int row = wn * 64 + (QN * 2 + i2) * 16 + lr;                           \
            _Pragma("unroll") for (int kk = 0; kk < 2; ++kk)                             \
                bfr[i2][kk] = *(const bf16x8*)(curB + row * 64 + (((kk * 4 + lg) ^ (lr & 7)) << 3)); \
        }                                                                                \
        STAGE_STMT;                                                                      \
        if (DO_VM) asm volatile("s_waitcnt vmcnt(4)" ::: "memory");                      \
        __builtin_amdgcn_s_barrier();                                                    \
        asm volatile("s_waitcnt lgkmcnt(0)" ::: "memory");                               \
        __builtin_amdgcn_sched_barrier(0);                                               \
        __builtin_amdgcn_s_setprio(1);                                                   \
        _Pragma("unroll") for (int i = 0; i < 4; ++i)                                    \
            _Pragma("unroll") for (int i2 = 0; i2 < 2; ++i2)                             \
                _Pragma("unroll") for (int kk = 0; kk < 2; ++kk)                         \
                    acc[QM * 4 + i][QN * 2 + i2] = __builtin_amdgcn_mfma_f32_16x16x32_bf16( \
                        af[i][kk], bfr[i2][kk], acc[QM * 4 + i][QN * 2 + i2], 0, 0, 0);  \
        __builtin_amdgcn_s_setprio(0);                                                   \
        __builtin_amdgcn_s_barrier();                                                    \
    }

template <typename CT>
__global__ __launch_bounds__(512, 2) void gemm_bt256_kernel(const bf16* __restrict__ A,
                                                            const bf16* __restrict__ Bm,
                                                            CT* __restrict__ C,
                                                            int M, int N, int K) {
    __shared__ bf16 sm[65536];   // 128 KiB
    const int nbx = N >> 8;
    const int cpx = gridDim.x >> 3;
    const int bid = blockIdx.x;
    const int swz = (bid & 7) * cpx + (bid >> 3);       // XCD swizzle (grid % 8 == 0)
    const int m0 = (swz / nbx) << 8;
    const int n0 = (swz % nbx) << 8;

    const int tid = threadIdx.x;
    const int w = tid >> 6, lane = tid & 63;
    const int wm = w >> 2, wn = w & 3;                  // 2 x 4 wave grid, 128x64 per wave
    const int lg = lane >> 4, lr = lane & 15;
    const int nkt = K >> 6;

    const bf16* Ab = A + (size_t)m0 * K;
    const bf16* Bb = Bm + (size_t)n0 * K;

    const int u8 = tid >> 3;
    const int schunk = ((tid & 7) ^ (u8 & 7)) << 3;     // pre-swizzled source col offset

    auto stageA = [&](int buf, int kt, int h) {
        bf16* dst = sm + buf * 32768 + h * 4096 + tid * 8;
        const bf16* src = Ab + (size_t)(h * 64 + u8) * K + kt * 64 + schunk;
        gload_lds16(src, dst);
        gload_lds16(src + (size_t)128 * K, dst + 8192);
    };
    auto stageB = [&](int buf, int kt, int h) {
        bf16* dst = sm + buf * 32768 + 16384 + h * 2048 + ((u8 >> 5) << 12) + ((u8 & 31) << 6) + ((tid & 7) << 3);
        const bf16* src = Bb + (size_t)(h * 32 + ((u8 >> 5) << 6) + (u8 & 31)) * K + kt * 64 + schunk;
        gload_lds16(src, dst);
        gload_lds16(src + (size_t)128 * K, dst + 8192);
    };

    f32x4 acc[8][4] = {};

    // prologue: tile0 fully -> buf0 (8 loads); tile1 B0,A0 -> buf1 (4 loads)
    stageA(0, 0, 0); stageA(0, 0, 1); stageB(0, 0, 0); stageB(0, 0, 1);
    stageB(1, 1, 0); stageA(1, 1, 0);
    asm volatile("s_waitcnt vmcnt(4)" ::: "memory");    // tile0 landed; tile1's 4 in flight
    __builtin_amdgcn_s_barrier();

    for (int t = 0; t < nkt; ++t) {
        const int cur = t & 1;
        const bf16* curA = sm + cur * 32768;
        const bf16* curB = curA + 16384;
        PHASE256(0, 0, { if (t + 1 < nkt) stageA(cur ^ 1, t + 1, 1); }, 0)
        PHASE256(1, 0, { if (t + 1 < nkt) stageB(cur ^ 1, t + 1, 1); }, 0)
        PHASE256(0, 1, { if (t + 2 < nkt) stageB(cur, t + 2, 0); }, 0)
        PHASE256(1, 1, { if (t + 2 < nkt) stageA(cur, t + 2, 0); }, 1)
    }

    #pragma unroll
    for (int mi = 0; mi < 8; ++mi)
        #pragma unroll
        for (int ni = 0; ni < 4; ++ni)
            #pragma unroll
            for (int r = 0; r < 4; ++r) {
                const int row = m0 + wm * 128 + mi * 16 + lg * 4 + r;
                const int col = n0 + wn * 64 + ni * 16 + lr;
                C[(size_t)row * N + col] = (CT)acc[mi][ni][r];
            }
}

// ---------------- flash attention (causal, GQA) ----------------
// Block = 256 threads = 4 waves = 4 q-heads of one GQA group, same 32 q-rows.
// SWAPPED QK^T: st = mfma(K, Q) -> D[k][q]; lane (lg,lr) holds k = kt*16+lg*4+r
// for q-column lr. Softmax max/sum = in-register (15 ops) + 2 shfl (xor16,32).
// fac/rowsum cross to acc's q=lg*4+r rows via 1 bpermute each (rescale is rare).
#define KVB_ 64

__global__ __launch_bounds__(256) void attn_kernel(const bf16* __restrict__ Q,
                                                   const bf16* __restrict__ Kb,
                                                   const bf16* __restrict__ Vt,
                                                   bf16* __restrict__ O) {
    __shared__ bf16 lds[24576];   // Ks[64][128] | Vs[128][64] | pbuf 4 x [32][64]
    bf16* Ks = lds;
    bf16* Vs = lds + 8192;

    const int flat = blockIdx.x;
    const int x = flat & 7;
    const int j = flat >> 3;
    const int hkb = x * 2 + (j & 1);
    const int qt = 63 - (j >> 1);
    const int hk = hkb & 7, b = hkb >> 3;
    const int q0 = qt * 32;

    const int tid = threadIdx.x;
    const int w = tid >> 6, lane = tid & 63;
    const int lg = lane >> 4, lr = lane & 15;
    const int h = hk * 4 + w;
    bf16* pb = lds + 16384 + w * 2048;

    const bf16* qbase = Q + ((size_t)(b * S_ + q0 + lr)) * QKVS + h * HD_ + lg * 8;
    bf16x8 qf[2][4];
    #pragma unroll
    for (int m = 0; m < 2; m++)
        #pragma unroll
        for (int kk = 0; kk < 4; kk++)
            qf[m][kk] = *(const bf16x8*)(qbase + (size_t)m * 16 * QKVS + kk * 32);

    const bf16* Kh = Kb + ((size_t)b * S_) * QKVS + hk * HD_;
    const bf16* Vh = Vt + ((size_t)(b * HKV_ + hk)) * HD_ * S_;

    const int krow_s  = tid >> 4;
    const int kchnk_s = (tid & 15) ^ (tid >> 4);
    const int vrow_s  = tid >> 3;
    const int vchnk_s = (tid & 7) ^ ((tid >> 3) & 7);

    f32x4 acc[2][8];
    #pragma unroll
    for (int m = 0; m < 2; m++)
        #pragma unroll
        for (int dt = 0; dt < 8; dt++)
            acc[m][dt] = (f32x4){0.f, 0.f, 0.f, 0.f};
    float rowmax[2], rowsum[2];   // per-lane: stats for q-column = m*16 + lr
    #pragma unroll
    for (int m = 0; m < 2; m++) { rowmax[m] = -1e30f; rowsum[m] = 0.f; }

    const float scale = 0.08838834764831845f;
    const int nt = (q0 + 32 + KVB_ - 1) / KVB_;

    for (int it = 0; it < nt; ++it) {
        const int k0 = it * KVB_;
        #pragma unroll
        for (int jj = 0; jj < 4; jj++)
            gload_lds16(Kh + (size_t)(k0 + jj * 16 + krow_s) * QKVS + kchnk_s * 8,
                        Ks + jj * 2048 + tid * 8);
        #pragma unroll
        for (int jj = 0; jj < 4; jj++)
            gload_lds16(Vh + (size_t)(jj * 32 + vrow_s) * S_ + k0 + vchnk_s * 8,
                        Vs + jj * 2048 + tid * 8);
        __syncthreads();

        // ---- QK^T swapped: st[m][kt] = K_tile^T x Q -> D[k][q] ----
        f32x4 st[2][4];
        #pragma unroll
        for (int m = 0; m < 2; m++)
            #pragma unroll
            for (int kt = 0; kt < 4; kt++)
                st[m][kt] = (f32x4){0.f, 0.f, 0.f, 0.f};
        #pragma unroll
        for (int kt = 0; kt < 4; kt++) {
            bf16x8 kf[4];
            #pragma unroll
            for (int kk = 0; kk < 4; kk++)
                kf[kk] = *(const bf16x8*)(Ks + (kt * 16 + lr) * 128 + (((kk * 4 + lg) ^ lr) << 3));
            #pragma unroll
            for (int m = 0; m < 2; m++)
                #pragma unroll
                for (int kk = 0; kk < 4; kk++)
                    st[m][kt] = __builtin_amdgcn_mfma_f32_16x16x32_bf16(kf[kk], qf[m][kk], st[m][kt], 0, 0, 0);
        }

        // ---- scale + causal mask (D layout: row = k = kt*16+lg*4+r, col = q = m*16+lr) ----
        const bool need_mask = (k0 + KVB_ - 1 > q0);
        #pragma unroll
        for (int m = 0; m < 2; m++)
            #pragma unroll
            for (int kt = 0; kt < 4; kt++)
                #pragma unroll
                for (int r = 0; r < 4; r++) {
                    float s = st[m][kt][r] * scale;
                    if (need_mask) {
                        const int qg = q0 + m * 16 + lr;
                        const int kg = k0 + kt * 16 + lg * 4 + r;
                        s = (kg <= qg) ? s : -1e30f;
                    }
                    st[m][kt][r] = s;
                }

        // ---- online softmax: in-lane reduce (16 vals) + 2 shfl, T13 defer-max ----
        float vmax[2];
        #pragma unroll
        for (int m = 0; m < 2; m++) {
            float v = st[m][0][0];
            #pragma unroll
            for (int kt = 0; kt < 4; kt++)
                #pragma unroll
                for (int r = 0; r < 4; r++)
                    v = fmaxf(v, st[m][kt][r]);
            v = fmaxf(v, __shfl_xor(v, 16));
            v = fmaxf(v, __shfl_xor(v, 32));
            vmax[m] = v;
        }
        const bool upd = (vmax[0] > rowmax[0] + 8.0f) || (vmax[1] > rowmax[1] + 8.0f);
        if (__any(upd)) {
            #pragma unroll
            for (int m = 0; m < 2; m++) {
                const float mn = fmaxf(rowmax[m], vmax[m]);
                const float fac = __expf(rowmax[m] - mn);
                rowmax[m] = mn;
                rowsum[m] *= fac;
                // redistribute fac (per q=lr) to acc rows q = lg*4+r
                #pragma unroll
                for (int r = 0; r < 4; r++) {
                    const float facr = __shfl(fac, lg * 4 + r);
                    #pragma unroll
                    for (int dt = 0; dt < 8; dt++)
                        acc[m][dt][r] *= facr;
                }
            }
        }
        #pragma unroll
        for (int m = 0; m < 2; m++) {
            float ssum = 0.f;
            #pragma unroll
            for (int kt = 0; kt < 4; kt++)
                #pragma unroll
                for (int r = 0; r < 4; r++) {
                    const float pv = __expf(st[m][kt][r] - rowmax[m]);
                    st[m][kt][r] = pv;
                    ssum += pv;
                }
            ssum += __shfl_xor(ssum, 16);
            ssum += __shfl_xor(ssum, 32);
            rowsum[m] += ssum;
        }

        // ---- P -> per-wave pbuf [32 q][64 k], elem ^= (qrow&7)<<3 ----
        #pragma unroll
        for (int m = 0; m < 2; m++) {
            const int qrow = m * 16 + lr;
            #pragma unroll
            for (int kt = 0; kt < 4; kt++)
                #pragma unroll
                for (int r = 0; r < 4; r++)
                    pb[(qrow * 64 + kt * 16 + lg * 4 + r) ^ ((qrow & 7) << 3)] = (bf16)st[m][kt][r];
        }

        // ---- PV: read P as A-frag (row=q), V^T rows as B-frag ----
        bf16x8 pf[2][2];
        #pragma unroll
        for (int m = 0; m < 2; m++)
            #pragma unroll
            for (int ks = 0; ks < 2; ks++)
                pf[m][ks] = *(const bf16x8*)(pb + (m * 16 + lr) * 64 + ((ks * 32 + lg * 8) ^ ((lr & 7) << 3)));
        #pragma unroll
        for (int dt = 0; dt < 8; dt++) {
            bf16x8 vf[2];
            #pragma unroll
            for (int ks = 0; ks < 2; ks++)
                vf[ks] = *(const bf16x8*)(Vs + (dt * 16 + lr) * 64 + (((ks * 4 + lg) ^ (lr & 7)) << 3));
            #pragma unroll
            for (int m = 0; m < 2; m++)
                #pragma unroll
                for (int ks = 0; ks < 2; ks++)
                    acc[m][dt] = __builtin_amdgcn_mfma_f32_16x16x32_bf16(pf[m][ks], vf[ks], acc[m][dt], 0, 0, 0);
        }
        __syncthreads();
    }

    // ---- write O (acc rows q = lg*4+r need rowsum from lane lr'=lg*4+r) ----
    #pragma unroll
    for (int m = 0; m < 2; m++) {
        float inv[4];
        #pragma unroll
        for (int r = 0; r < 4; r++)
            inv[r] = 1.0f / __shfl(rowsum[m], lg * 4 + r);
        #pragma unroll
        for (int dt = 0; dt < 8; dt++)
            #pragma unroll
            for (int r = 0; r < 4; r++) {
                const size_t row = (size_t)(b * S_ + q0 + m * 16 + lg * 4 + r);
                O[row * (H_ * HD_) + h * HD_ + dt * 16 + lr] = (bf16)(acc[m][dt][r] * inv[r]);
            }
    }
}

// ---------------- launch ----------------

extern "C" void kernel_launch(void* const* d_in, const int* in_sizes, int n_in,
                              void* d_out, int out_size, void* d_ws, size_t ws_size,
                              hipStream_t stream) {
    const float* x  = (const float*)d_in[0];
    const float* Wq = (const float*)d_in[1];
    const float* Wk = (const float*)d_in[2];
    const float* Wv = (const float*)d_in[3];
    const float* Wo = (const float*)d_in[4];
    float* out = (float*)d_out;

    const size_t NX   = (size_t)B_ * S_ * D_;         // 16.78M elems
    const size_t NQKVW= (size_t)QKVS * D_;            // 25.2M elems (WqkvT)
    const size_t NQKV = (size_t)B_ * S_ * QKVS;       // 25.2M elems (QKV acts)
    const size_t NWK  = (size_t)D_ * HKV_ * HD_;      // 4.19M elems

    bf16* p = (bf16*)d_ws;
    bf16* xb    = p;  p += NX;       // x bf16; reused as attention output
    bf16* WqkvT = p;  p += NQKVW;    // [6144][4096]; reused as Vtb + WoT
    bf16* QKV   = p;  p += NQKV;     // [B*S][6144]
    bf16* Ab  = xb;                  // alias (xb dead after QKV GEMM)
    bf16* Vtb = WqkvT;               // alias (WqkvT dead after QKV GEMM), 4.19M elems
    bf16* WoT = WqkvT + NWK;         // alias, 16.78M elems

    // prep: cast x; build WqkvT = [WqT; WkT; WvT]
    cast_f32_bf16_kernel<<<(int)(NX / 1024), 256, 0, stream>>>(x, xb, (int)NX);
    transpose_cast_kernel<<<dim3((H_ * HD_) / 32, D_ / 32), dim3(32, 8), 0, stream>>>(Wq, WqkvT, D_, H_ * HD_);
    transpose_cast_kernel<<<dim3((HKV_ * HD_) / 32, D_ / 32), dim3(32, 8), 0, stream>>>(Wk, WqkvT + (size_t)(H_ * HD_) * D_, D_, HKV_ * HD_);
    transpose_cast_kernel<<<dim3((HKV_ * HD_) / 32, D_ / 32), dim3(32, 8), 0, stream>>>(Wv, WqkvT + (size_t)(H_ * HD_ + HKV_ * HD_) * D_, D_, HKV_ * HD_);

    // fused QKV projection: M=4096, N=6144, K=4096 (384 blocks, %8==0)
    gemm_bt256_kernel<bf16><<<384, 512, 0, stream>>>(xb, WqkvT, QKV, B_ * S_, QKVS, D_);

    // rope on Q (cols 0..4095) and K (cols 4096..5119)
    rope_kernel<<<B_ * S_, 256, 0, stream>>>(QKV, H_, QKVS);
    rope_kernel<<<B_ * S_, 256, 0, stream>>>(QKV + H_ * HD_, HKV_, QKVS);

    // V transpose (V = cols 5120.. of QKV)
    transpose_v_kernel<<<dim3(HD_ / 32, S_ / 32, B_ * HKV_), dim3(32, 8), 0, stream>>>(QKV + H_ * HD_ + HKV_ * HD_, Vtb);

    // attention: Q at QKV col 0, K at col 4096; both stride QKVS
    attn_kernel<<<1024, 256, 0, stream>>>(QKV, QKV + H_ * HD_, Vtb, Ab);

    // output projection
    transpose_cast_kernel<<<dim3(D_ / 32, (H_ * HD_) / 32), dim3(32, 8), 0, stream>>>(Wo, WoT, H_ * HD_, D_);
    gemm_bt256_kernel<float><<<256, 512, 0, stream>>>(Ab, WoT, out, B_ * S_, D_, H_ * HD_);
}

// Round 13
// 604.081 us; speedup vs baseline: 1.2674x; 1.0911x over previous
//
#include <hip/hip_runtime.h>
#include <hip/hip_bf16.h>

// Problem constants
#define B_   2
#define S_   2048
#define D_   4096
#define H_   32
#define HKV_ 8
#define HD_  128
#define QKVS 6144   // fused QKV row stride (H*HD + 2*HKV*HD)

typedef __bf16 bf16;
typedef __bf16 bf16x8 __attribute__((ext_vector_type(8)));
typedef __bf16 bf16x4 __attribute__((ext_vector_type(4)));
typedef float  f32x4  __attribute__((ext_vector_type(4)));

// ---------------- prep kernels ----------------

__global__ void cast_f32_bf16_kernel(const float* __restrict__ in, bf16* __restrict__ out, int n) {
    int i = (blockIdx.x * blockDim.x + threadIdx.x) * 4;
    if (i >= n) return;
    const float4 v = *(const float4*)(in + i);
    bf16x4 o;
    o[0] = (bf16)v.x; o[1] = (bf16)v.y; o[2] = (bf16)v.z; o[3] = (bf16)v.w;
    *(bf16x4*)(out + i) = o;
}

// W: K x N fp32 row-major  ->  WT: N x K bf16 row-major
__global__ void transpose_cast_kernel(const float* __restrict__ W, bf16* __restrict__ WT, int K, int N) {
    __shared__ float t[32][33];
    const int n0 = blockIdx.x * 32, k0 = blockIdx.y * 32;
    const int tx = threadIdx.x, ty = threadIdx.y;
    #pragma unroll
    for (int i = ty; i < 32; i += 8) t[i][tx] = W[(size_t)(k0 + i) * N + n0 + tx];
    __syncthreads();
    #pragma unroll
    for (int i = ty; i < 32; i += 8) WT[(size_t)(n0 + i) * K + k0 + tx] = (bf16)t[tx][i];
}

// V (cols 5120.. of QKV, row stride QKVS) -> Vt: (b,hk,d) x s bf16
__global__ void transpose_v_kernel(const bf16* __restrict__ V, bf16* __restrict__ Vt) {
    __shared__ bf16 t[32][33];
    const int bh = blockIdx.z;            // b*HKV + hk
    const int b = bh >> 3, hk = bh & 7;
    const int d0 = blockIdx.x * 32, s0 = blockIdx.y * 32;
    const int tx = threadIdx.x, ty = threadIdx.y;
    #pragma unroll
    for (int i = ty; i < 32; i += 8)
        t[i][tx] = V[((size_t)(b * S_ + s0 + i)) * QKVS + hk * HD_ + d0 + tx];
    __syncthreads();
    #pragma unroll
    for (int i = ty; i < 32; i += 8)
        Vt[((size_t)(bh * HD_ + d0 + i)) * S_ + s0 + tx] = t[tx][i];
}

// rotate-half RoPE in place on rows of a strided matrix, pos = row % S
__global__ void rope_kernel(bf16* __restrict__ T, int nh, int stride) {
    const int row = blockIdx.x;
    const int pos = row & (S_ - 1);
    const size_t base = (size_t)row * stride;
    const int npairs = nh * 64;
    const float c = 13.287712379549449f / 64.0f;   // log2(10000)/64
    for (int p = threadIdx.x; p < npairs; p += blockDim.x) {
        const int h = p >> 6, d = p & 63;
        const float invf = exp2f(-(float)d * c);
        const float ang = (float)pos * invf;
        float sn, cs;
        sincosf(ang, &sn, &cs);
        const size_t i1 = base + (size_t)h * HD_ + d;
        const size_t i2 = i1 + 64;
        const float a  = (float)T[i1];
        const float b2 = (float)T[i2];
        T[i1] = (bf16)(a * cs - b2 * sn);
        T[i2] = (bf16)(b2 * cs + a * sn);
    }
}

__device__ __forceinline__ void gload_lds16(const bf16* g, bf16* l) {
    __builtin_amdgcn_global_load_lds((const __attribute__((address_space(1))) void*)g,
                                     (__attribute__((address_space(3))) void*)l, 16, 0, 0);
}

// ---------------- GEMM 128x128 (m97 structure) — KV projection ----------------
// Cs = C row stride (may differ from logical N for strided output)

template <typename CT>
__global__ __launch_bounds__(256) void gemm_bt_kernel(const bf16* __restrict__ A,
                                                      const bf16* __restrict__ Bm,
                                                      CT* __restrict__ C,
                                                      int M, int Cs, int K) {
    __shared__ bf16 As[128 * 32];
    __shared__ bf16 Bs[128 * 32];
    const int m0 = blockIdx.x * 128, n0 = blockIdx.y * 128;
    const int tid = threadIdx.x;
    const int lane = tid & 63, wid = tid >> 6;
    const int wm = wid >> 1, wn = wid & 1;       // 2x2 waves -> 64x64 each
    const int lg = lane >> 4, lr = lane & 15;
    f32x4 acc[4][4] = {};
    const int arow = tid >> 2;
    const int achunk = (tid & 3) * 8;
    for (int k0 = 0; k0 < K; k0 += 32) {
        gload_lds16(A  + (size_t)(m0 + arow) * K      + k0 + achunk, As + tid * 8);
        gload_lds16(A  + (size_t)(m0 + 64 + arow) * K + k0 + achunk, As + 2048 + tid * 8);
        gload_lds16(Bm + (size_t)(n0 + arow) * K      + k0 + achunk, Bs + tid * 8);
        gload_lds16(Bm + (size_t)(n0 + 64 + arow) * K + k0 + achunk, Bs + 2048 + tid * 8);
        __syncthreads();
        bf16x8 af[4], bfv[4];
        #pragma unroll
        for (int i = 0; i < 4; i++) {
            af[i]  = *(const bf16x8*)(As + (wm * 64 + i * 16 + lr) * 32 + lg * 8);
            bfv[i] = *(const bf16x8*)(Bs + (wn * 64 + i * 16 + lr) * 32 + lg * 8);
        }
        #pragma unroll
        for (int mi = 0; mi < 4; mi++)
            #pragma unroll
            for (int ni = 0; ni < 4; ni++)
                acc[mi][ni] = __builtin_amdgcn_mfma_f32_16x16x32_bf16(af[mi], bfv[ni], acc[mi][ni], 0, 0, 0);
        __syncthreads();
    }
    #pragma unroll
    for (int mi = 0; mi < 4; mi++)
        #pragma unroll
        for (int ni = 0; ni < 4; ni++)
            #pragma unroll
            for (int r = 0; r < 4; r++) {
                const int row = m0 + wm * 64 + mi * 16 + lg * 4 + r;
                const int col = n0 + wn * 64 + ni * 16 + lr;
                C[(size_t)row * Cs + col] = (CT)acc[mi][ni][r];
            }
}

// ---------------- GEMM 256x256, BK=64, 8 waves, 4-phase pipelined + quadrant reg-cache ----
// Phase order (0,0),(0,1),(1,0),(1,1): A-quad read once per half (phases A,C),
// B-quads cached across phases (b0: A->C, b1: B->D). 24 ds_read_b128/K-tile/wave.
// Stage points & vmcnt(4) bookkeeping identical to the proven round-8 schedule;
// extra vmcnt(0) before the last tile closes the tail-latency race.

template <typename CT>
__global__ __launch_bounds__(512, 2) void gemm_bt256_kernel(const bf16* __restrict__ A,
                                                            const bf16* __restrict__ Bm,
                                                            CT* __restrict__ C,
                                                            int M, int N, int K, int Cs) {
    __shared__ bf16 sm[65536];   // 128 KiB
    const int nbx = N >> 8;
    const int cpx = gridDim.x >> 3;
    const int bid = blockIdx.x;
    const int swz = (bid & 7) * cpx + (bid >> 3);       // XCD swizzle (grid % 8 == 0)
    const int m0 = (swz / nbx) << 8;
    const int n0 = (swz % nbx) << 8;

    const int tid = threadIdx.x;
    const int w = tid >> 6, lane = tid & 63;
    const int wm = w >> 2, wn = w & 3;                  // 2 x 4 wave grid, 128x64 per wave
    const int lg = lane >> 4, lr = lane & 15;
    const int nkt = K >> 6;

    const bf16* Ab = A + (size_t)m0 * K;
    const bf16* Bb = Bm + (size_t)n0 * K;

    const int u8 = tid >> 3;
    const int schunk = ((tid & 7) ^ (u8 & 7)) << 3;     // pre-swizzled source col offset

    auto stageA = [&](int buf, int kt, int h) {
        bf16* dst = sm + buf * 32768 + h * 4096 + tid * 8;
        const bf16* src = Ab + (size_t)(h * 64 + u8) * K + kt * 64 + schunk;
        gload_lds16(src, dst);
        gload_lds16(src + (size_t)128 * K, dst + 8192);
    };
    auto stageB = [&](int buf, int kt, int h) {
        bf16* dst = sm + buf * 32768 + 16384 + h * 2048 + ((u8 >> 5) << 12) + ((u8 & 31) << 6) + ((tid & 7) << 3);
        const bf16* src = Bb + (size_t)(h * 32 + ((u8 >> 5) << 6) + (u8 & 31)) * K + kt * 64 + schunk;
        gload_lds16(src, dst);
        gload_lds16(src + (size_t)128 * K, dst + 8192);
    };

    f32x4 acc[8][4] = {};

    // prologue: tile0 fully -> buf0 (8 loads); tile1 B0,A0 -> buf1 (4 loads)
    stageA(0, 0, 0); stageA(0, 0, 1); stageB(0, 0, 0); stageB(0, 0, 1);
    stageB(1, 1, 0); stageA(1, 1, 0);
    asm volatile("s_waitcnt vmcnt(4)" ::: "memory");    // tile0 landed; tile1's 4 in flight
    __builtin_amdgcn_s_barrier();

    #define MFMA_Q(MI0, NI0, AREG, BREG)                                                     \
        __builtin_amdgcn_s_setprio(1);                                                       \
        _Pragma("unroll") for (int i = 0; i < 4; ++i)                                        \
            _Pragma("unroll") for (int i2 = 0; i2 < 2; ++i2)                                 \
                _Pragma("unroll") for (int kk = 0; kk < 2; ++kk)                             \
                    acc[MI0 + i][NI0 + i2] = __builtin_amdgcn_mfma_f32_16x16x32_bf16(        \
                        AREG[i][kk], BREG[i2][kk], acc[MI0 + i][NI0 + i2], 0, 0, 0);         \
        __builtin_amdgcn_s_setprio(0);                                                       \
        __builtin_amdgcn_s_barrier();

    #define SYNC_IN()                                                                        \
        __builtin_amdgcn_s_barrier();                                                        \
        asm volatile("s_waitcnt lgkmcnt(0)" ::: "memory");                                   \
        __builtin_amdgcn_sched_barrier(0);

    for (int t = 0; t < nkt; ++t) {
        const int cur = t & 1;
        const bf16* curA = sm + cur * 32768;
        const bf16* curB = curA + 16384;
        bf16x8 afc[4][2], b0[2][2], b1[2][2];

        // ---- Phase A: (0,0). Read+cache A-quad0, B-quad0. Stage A1(t+1)->other.
        #pragma unroll
        for (int i = 0; i < 4; ++i) {
            const int row = wm * 128 + i * 16 + lr;
            #pragma unroll
            for (int kk = 0; kk < 2; ++kk)
                afc[i][kk] = *(const bf16x8*)(curA + row * 64 + (((kk * 4 + lg) ^ (lr & 7)) << 3));
        }
        #pragma unroll
        for (int i2 = 0; i2 < 2; ++i2) {
            const int row = wn * 64 + i2 * 16 + lr;
            #pragma unroll
            for (int kk = 0; kk < 2; ++kk)
                b0[i2][kk] = *(const bf16x8*)(curB + row * 64 + (((kk * 4 + lg) ^ (lr & 7)) << 3));
        }
        if (t + 1 < nkt) stageA(cur ^ 1, t + 1, 1);
        if (t + 1 == nkt) asm volatile("s_waitcnt vmcnt(0)" ::: "memory");  // final-tile drain
        SYNC_IN()
        MFMA_Q(0, 0, afc, b0)

        // ---- Phase B: (0,1). Read+cache B-quad1. Stage B1(t+1)->other.
        #pragma unroll
        for (int i2 = 0; i2 < 2; ++i2) {
            const int row = wn * 64 + (2 + i2) * 16 + lr;
            #pragma unroll
            for (int kk = 0; kk < 2; ++kk)
                b1[i2][kk] = *(const bf16x8*)(curB + row * 64 + (((kk * 4 + lg) ^ (lr & 7)) << 3));
        }
        if (t + 1 < nkt) stageB(cur ^ 1, t + 1, 1);
        SYNC_IN()
        MFMA_Q(0, 2, afc, b1)

        // ---- Phase C: (1,0). Read A-quad1 (overwrite cache); b0 still cached. Stage B0(t+2)->cur.
        #pragma unroll
        for (int i = 0; i < 4; ++i) {
            const int row = wm * 128 + (4 + i) * 16 + lr;
            #pragma unroll
            for (int kk = 0; kk < 2; ++kk)
                afc[i][kk] = *(const bf16x8*)(curA + row * 64 + (((kk * 4 + lg) ^ (lr & 7)) << 3));
        }
        if (t + 2 < nkt) stageB(cur, t + 2, 0);
        SYNC_IN()
        MFMA_Q(4, 0, afc, b0)

        // ---- Phase D: (1,1). No LDS reads (afc=A1, b1 cached). Stage A0(t+2)->cur; counted wait.
        if (t + 2 < nkt) stageA(cur, t + 2, 0);
        asm volatile("s_waitcnt vmcnt(4)" ::: "memory");
        SYNC_IN()
        MFMA_Q(4, 2, afc, b1)
    }
    #undef MFMA_Q
    #undef SYNC_IN

    #pragma unroll
    for (int mi = 0; mi < 8; ++mi)
        #pragma unroll
        for (int ni = 0; ni < 4; ++ni)
            #pragma unroll
            for (int r = 0; r < 4; ++r) {
                const int row = m0 + wm * 128 + mi * 16 + lg * 4 + r;
                const int col = n0 + wn * 64 + ni * 16 + lr;
                C[(size_t)row * Cs + col] = (CT)acc[mi][ni][r];
            }
}

// ---------------- flash attention (causal, GQA) — swapped QK^T ----------------
#define KVB_ 64

__global__ __launch_bounds__(256) void attn_kernel(const bf16* __restrict__ Q,
                                                   const bf16* __restrict__ Kb,
                                                   const bf16* __restrict__ Vt,
                                                   bf16* __restrict__ O) {
    __shared__ bf16 lds[24576];   // Ks[64][128] | Vs[128][64] | pbuf 4 x [32][64]
    bf16* Ks = lds;
    bf16* Vs = lds + 8192;

    const int flat = blockIdx.x;
    const int x = flat & 7;
    const int j = flat >> 3;
    const int hkb = x * 2 + (j & 1);
    const int qt = 63 - (j >> 1);
    const int hk = hkb & 7, b = hkb >> 3;
    const int q0 = qt * 32;

    const int tid = threadIdx.x;
    const int w = tid >> 6, lane = tid & 63;
    const int lg = lane >> 4, lr = lane & 15;
    const int h = hk * 4 + w;
    bf16* pb = lds + 16384 + w * 2048;

    const bf16* qbase = Q + ((size_t)(b * S_ + q0 + lr)) * QKVS + h * HD_ + lg * 8;
    bf16x8 qf[2][4];
    #pragma unroll
    for (int m = 0; m < 2; m++)
        #pragma unroll
        for (int kk = 0; kk < 4; kk++)
            qf[m][kk] = *(const bf16x8*)(qbase + (size_t)m * 16 * QKVS + kk * 32);

    const bf16* Kh = Kb + ((size_t)b * S_) * QKVS + hk * HD_;
    const bf16* Vh = Vt + ((size_t)(b * HKV_ + hk)) * HD_ * S_;

    const int krow_s  = tid >> 4;
    const int kchnk_s = (tid & 15) ^ (tid >> 4);
    const int vrow_s  = tid >> 3;
    const int vchnk_s = (tid & 7) ^ ((tid >> 3) & 7);

    f32x4 acc[2][8];
    #pragma unroll
    for (int m = 0; m < 2; m++)
        #pragma unroll
        for (int dt = 0; dt < 8; dt++)
            acc[m][dt] = (f32x4){0.f, 0.f, 0.f, 0.f};
    float rowmax[2], rowsum[2];   // per-lane: stats for q-column = m*16 + lr
    #pragma unroll
    for (int m = 0; m < 2; m++) { rowmax[m] = -1e30f; rowsum[m] = 0.f; }

    const float scale = 0.08838834764831845f;
    const int nt = (q0 + 32 + KVB_ - 1) / KVB_;

    for (int it = 0; it < nt; ++it) {
        const int k0 = it * KVB_;
        #pragma unroll
        for (int jj = 0; jj < 4; jj++)
            gload_lds16(Kh + (size_t)(k0 + jj * 16 + krow_s) * QKVS + kchnk_s * 8,
                        Ks + jj * 2048 + tid * 8);
        #pragma unroll
        for (int jj = 0; jj < 4; jj++)
            gload_lds16(Vh + (size_t)(jj * 32 + vrow_s) * S_ + k0 + vchnk_s * 8,
                        Vs + jj * 2048 + tid * 8);
        __syncthreads();

        // ---- QK^T swapped: st[m][kt] = K_tile^T x Q -> D[k][q] ----
        f32x4 st[2][4];
        #pragma unroll
        for (int m = 0; m < 2; m++)
            #pragma unroll
            for (int kt = 0; kt < 4; kt++)
                st[m][kt] = (f32x4){0.f, 0.f, 0.f, 0.f};
        #pragma unroll
        for (int kt = 0; kt < 4; kt++) {
            bf16x8 kf[4];
            #pragma unroll
            for (int kk = 0; kk < 4; kk++)
                kf[kk] = *(const bf16x8*)(Ks + (kt * 16 + lr) * 128 + (((kk * 4 + lg) ^ lr) << 3));
            #pragma unroll
            for (int m = 0; m < 2; m++)
                #pragma unroll
                for (int kk = 0; kk < 4; kk++)
                    st[m][kt] = __builtin_amdgcn_mfma_f32_16x16x32_bf16(kf[kk], qf[m][kk], st[m][kt], 0, 0, 0);
        }

        // ---- scale + causal mask (D: row = k = kt*16+lg*4+r, col = q = m*16+lr) ----
        const bool need_mask = (k0 + KVB_ - 1 > q0);
        #pragma unroll
        for (int m = 0; m < 2; m++)
            #pragma unroll
            for (int kt = 0; kt < 4; kt++)
                #pragma unroll
                for (int r = 0; r < 4; r++) {
                    float s = st[m][kt][r] * scale;
                    if (need_mask) {
                        const int qg = q0 + m * 16 + lr;
                        const int kg = k0 + kt * 16 + lg * 4 + r;
                        s = (kg <= qg) ? s : -1e30f;
                    }
                    st[m][kt][r] = s;
                }

        // ---- online softmax: in-lane reduce + 2 shfl, T13 defer-max ----
        float vmax[2];
        #pragma unroll
        for (int m = 0; m < 2; m++) {
            float v = st[m][0][0];
            #pragma unroll
            for (int kt = 0; kt < 4; kt++)
                #pragma unroll
                for (int r = 0; r < 4; r++)
                    v = fmaxf(v, st[m][kt][r]);
            v = fmaxf(v, __shfl_xor(v, 16));
            v = fmaxf(v, __shfl_xor(v, 32));
            vmax[m] = v;
        }
        const bool upd = (vmax[0] > rowmax[0] + 8.0f) || (vmax[1] > rowmax[1] + 8.0f);
        if (__any(upd)) {
            #pragma unroll
            for (int m = 0; m < 2; m++) {
                const float mn = fmaxf(rowmax[m], vmax[m]);
                const float fac = __expf(rowmax[m] - mn);
                rowmax[m] = mn;
                rowsum[m] *= fac;
                #pragma unroll
                for (int r = 0; r < 4; r++) {
                    const float facr = __shfl(fac, lg * 4 + r);
                    #pragma unroll
                    for (int dt = 0; dt < 8; dt++)
                        acc[m][dt][r] *= facr;
                }
            }
        }
        #pragma unroll
        for (int m = 0; m < 2; m++) {
            float ssum = 0.f;
            #pragma unroll
            for (int kt = 0; kt < 4; kt++)
                #pragma unroll
                for (int r = 0; r < 4; r++) {
                    const float pv = __expf(st[m][kt][r] - rowmax[m]);
                    st[m][kt][r] = pv;
                    ssum += pv;
                }
            ssum += __shfl_xor(ssum, 16);
            ssum += __shfl_xor(ssum, 32);
            rowsum[m] += ssum;
        }

        // ---- P -> per-wave pbuf [32 q][64 k], elem ^= (qrow&7)<<3 ----
        #pragma unroll
        for (int m = 0; m < 2; m++) {
            const int qrow = m * 16 + lr;
            #pragma unroll
            for (int kt = 0; kt < 4; kt++)
                #pragma unroll
                for (int r = 0; r < 4; r++)
                    pb[(qrow * 64 + kt * 16 + lg * 4 + r) ^ ((qrow & 7) << 3)] = (bf16)st[m][kt][r];
        }

        // ---- PV ----
        bf16x8 pf[2][2];
        #pragma unroll
        for (int m = 0; m < 2; m++)
            #pragma unroll
            for (int ks = 0; ks < 2; ks++)
                pf[m][ks] = *(const bf16x8*)(pb + (m * 16 + lr) * 64 + ((ks * 32 + lg * 8) ^ ((lr & 7) << 3)));
        #pragma unroll
        for (int dt = 0; dt < 8; dt++) {
            bf16x8 vf[2];
            #pragma unroll
            for (int ks = 0; ks < 2; ks++)
                vf[ks] = *(const bf16x8*)(Vs + (dt * 16 + lr) * 64 + (((ks * 4 + lg) ^ (lr & 7)) << 3));
            #pragma unroll
            for (int m = 0; m < 2; m++)
                #pragma unroll
                for (int ks = 0; ks < 2; ks++)
                    acc[m][dt] = __builtin_amdgcn_mfma_f32_16x16x32_bf16(pf[m][ks], vf[ks], acc[m][dt], 0, 0, 0);
        }
        __syncthreads();
    }

    // ---- write O ----
    #pragma unroll
    for (int m = 0; m < 2; m++) {
        float inv[4];
        #pragma unroll
        for (int r = 0; r < 4; r++)
            inv[r] = 1.0f / __shfl(rowsum[m], lg * 4 + r);
        #pragma unroll
        for (int dt = 0; dt < 8; dt++)
            #pragma unroll
            for (int r = 0; r < 4; r++) {
                const size_t row = (size_t)(b * S_ + q0 + m * 16 + lg * 4 + r);
                O[row * (H_ * HD_) + h * HD_ + dt * 16 + lr] = (bf16)(acc[m][dt][r] * inv[r]);
            }
    }
}

// ---------------- launch ----------------

extern "C" void kernel_launch(void* const* d_in, const int* in_sizes, int n_in,
                              void* d_out, int out_size, void* d_ws, size_t ws_size,
                              hipStream_t stream) {
    const float* x  = (const float*)d_in[0];
    const float* Wq = (const float*)d_in[1];
    const float* Wk = (const float*)d_in[2];
    const float* Wv = (const float*)d_in[3];
    const float* Wo = (const float*)d_in[4];
    float* out = (float*)d_out;

    const size_t NX   = (size_t)B_ * S_ * D_;         // 16.78M elems
    const size_t NQKVW= (size_t)QKVS * D_;            // 25.2M elems (WqkvT)
    const size_t NQKV = (size_t)B_ * S_ * QKVS;       // 25.2M elems (QKV acts)
    const size_t NWK  = (size_t)D_ * HKV_ * HD_;      // 4.19M elems

    bf16* p = (bf16*)d_ws;
    bf16* xb    = p;  p += NX;       // x bf16; reused as attention output
    bf16* WqkvT = p;  p += NQKVW;    // [6144][4096]; reused as Vtb + WoT
    bf16* QKV   = p;  p += NQKV;     // [B*S][6144]
    bf16* Ab  = xb;                  // alias (xb dead after projections)
    bf16* Vtb = WqkvT;               // alias (WqkvT dead after projections)
    bf16* WoT = WqkvT + NWK;         // alias

    // prep: cast x; build WqkvT = [WqT; WkT; WvT]
    cast_f32_bf16_kernel<<<(int)(NX / 1024), 256, 0, stream>>>(x, xb, (int)NX);
    transpose_cast_kernel<<<dim3((H_ * HD_) / 32, D_ / 32), dim3(32, 8), 0, stream>>>(Wq, WqkvT, D_, H_ * HD_);
    transpose_cast_kernel<<<dim3((HKV_ * HD_) / 32, D_ / 32), dim3(32, 8), 0, stream>>>(Wk, WqkvT + (size_t)(H_ * HD_) * D_, D_, HKV_ * HD_);
    transpose_cast_kernel<<<dim3((HKV_ * HD_) / 32, D_ / 32), dim3(32, 8), 0, stream>>>(Wv, WqkvT + (size_t)(H_ * HD_ + HKV_ * HD_) * D_, D_, HKV_ * HD_);

    // Q projection: 256 blocks (perfect single round), write QKV cols 0..4095
    gemm_bt256_kernel<bf16><<<256, 512, 0, stream>>>(xb, WqkvT, QKV, B_ * S_, H_ * HD_, D_, QKVS);
    // KV projection: 128^2 kernel, 512 blocks, write QKV cols 4096..6143
    gemm_bt_kernel<bf16><<<dim3(32, 16), 256, 0, stream>>>(xb, WqkvT + (size_t)(H_ * HD_) * D_,
                                                           QKV + H_ * HD_, B_ * S_, QKVS, D_);

    // rope on Q (cols 0..4095) and K (cols 4096..5119)
    rope_kernel<<<B_ * S_, 256, 0, stream>>>(QKV, H_, QKVS);
    rope_kernel<<<B_ * S_, 256, 0, stream>>>(QKV + H_ * HD_, HKV_, QKVS);

    // V transpose (V = cols 5120.. of QKV)
    transpose_v_kernel<<<dim3(HD_ / 32, S_ / 32, B_ * HKV_), dim3(32, 8), 0, stream>>>(QKV + H_ * HD_ + HKV_ * HD_, Vtb);

    // attention: Q at QKV col 0, K at col 4096; both stride QKVS
    attn_kernel<<<1024, 256, 0, stream>>>(QKV, QKV + H_ * HD_, Vtb, Ab);

    // output projection
    transpose_cast_kernel<<<dim3(D_ / 32, (H_ * HD_) / 32), dim3(32, 8), 0, stream>>>(Wo, WoT, H_ * HD_, D_);
    gemm_bt256_kernel<float><<<256, 512, 0, stream>>>(Ab, WoT, out, B_ * S_, D_, H_ * HD_, D_);
}